// Round 15
// baseline (9651.466 us; speedup 1.0000x reference)
//
#include <hip/hip_runtime.h>
#include <math.h>

#define NN 250000
#define NE 1250000
#define NC 50000
#define EMBD 200
#define NCH_E 245        // ceil(NN/1024) node chunks (edge CSR)
#define NCH_C 49         // ceil(NC/1024) crystal chunks
#define NBLK 22000       // edge-slot blocks (64 slots each)
#define NCBLK 6000       // crystal-slot blocks
#define SSTR  ((size_t)NBLK * 64)
#define SSTRC ((size_t)NCBLK * 64)

typedef unsigned int u32;
typedef unsigned short u16;
typedef short s16x8 __attribute__((ext_vector_type(8)));
typedef float f32x4 __attribute__((ext_vector_type(4)));

__device__ __forceinline__ u16 f2bf(float f) {
    u32 u = __float_as_uint(f);
    return (u16)((u + 0x7FFFu + ((u >> 16) & 1u)) >> 16);   // RNE
}
__device__ __forceinline__ float bf2f(u16 u) { return __uint_as_float(((u32)u) << 16); }
__device__ __forceinline__ u32 cvtpk(float lo, float hi) {
    u32 r;
    asm("v_cvt_pk_bf16_f32 %0, %1, %2" : "=v"(r) : "v"(lo), "v"(hi));
    return r;
}
__device__ __forceinline__ float lrelu(float v) { return v > 0.f ? v : 0.01f * v; }

// ---------- pack W[K][N] f32 -> fragment-major bf16 (B-operand, mfma_16x16x32) ----------
__global__ void k_pack(const float* __restrict__ src, u16* __restrict__ dst,
                       int K, int N, int nheads)
{
    const int t = blockIdx.x * 256 + threadIdx.x;
    const int F = (K / 32) * (N / 16);
    if (t >= nheads * F * 64) return;
    const int lane = t & 63;
    const int fh = t >> 6;
    const int f = fh % F, head = fh / F;
    const int ng = f % (N / 16), ks = f / (N / 16);
    const int q = lane >> 4, c = lane & 15;
    const float* s = src + (size_t)head * K * N;
    u16 o[8];
    #pragma unroll
    for (int i = 0; i < 8; ++i)
        o[i] = f2bf(s[(size_t)(32 * ks + 8 * q + i) * N + 16 * ng + c]);
    uint4 v;
    v.x = (u32)o[0] | ((u32)o[1] << 16);
    v.y = (u32)o[2] | ((u32)o[3] << 16);
    v.z = (u32)o[4] | ((u32)o[5] << 16);
    v.w = (u32)o[6] | ((u32)o[7] << 16);
    *(uint4*)(dst + (size_t)head * K * N + ((size_t)f * 64 + lane) * 8) = v;
}

// ---------- pack emb_w [200][63] -> frag-major bf16, K=224 N=64, zero-padded ----------
__global__ void k_packe(const float* __restrict__ src, u16* __restrict__ dst)
{
    const int t = blockIdx.x * 256 + threadIdx.x;
    if (t >= 28 * 64) return;
    const int lane = t & 63, f = t >> 6;
    const int ng = f & 3, ks = f >> 2;
    const int q = lane >> 4, c = lane & 15;
    u16 o[8];
    #pragma unroll
    for (int i = 0; i < 8; ++i) {
        const int kr = 32 * ks + 8 * q + i;
        const int col = 16 * ng + c;
        o[i] = (kr < EMBD && col < 63) ? f2bf(src[kr * 63 + col]) : (u16)0;
    }
    uint4 v;
    v.x = (u32)o[0] | ((u32)o[1] << 16);
    v.y = (u32)o[2] | ((u32)o[3] << 16);
    v.z = (u32)o[4] | ((u32)o[5] << 16);
    v.w = (u32)o[6] | ((u32)o[7] << 16);
    *(uint4*)(dst + ((size_t)f * 64 + lane) * 8) = v;
}

// ---------- pack W2[256][64] with the sH permutation ----------
__global__ void k_pack2(const float* __restrict__ src, u16* __restrict__ dst, int nheads)
{
    const int t = blockIdx.x * 256 + threadIdx.x;
    const int F = 32;
    if (t >= nheads * F * 64) return;
    const int lane = t & 63;
    const int fh = t >> 6;
    const int f = fh % F, head = fh / F;
    const int ks2 = f >> 2, ng = f & 3;
    const int q = lane >> 4, c = lane & 15;
    const int half = ks2 >> 2, k2l = ks2 & 3;
    const float* s = src + (size_t)head * 256 * 64;
    u16 o[8];
    #pragma unroll
    for (int i = 0; i < 8; ++i) {
        const int pl = 32 * k2l + 8 * q + i;
        const int krow = (pl >> 5) * 64 + (2 * half + (pl & 1)) * 16 + ((pl >> 1) & 15);
        o[i] = f2bf(s[(size_t)krow * 64 + 16 * ng + c]);
    }
    uint4 v;
    v.x = (u32)o[0] | ((u32)o[1] << 16);
    v.y = (u32)o[2] | ((u32)o[3] << 16);
    v.z = (u32)o[4] | ((u32)o[5] << 16);
    v.w = (u32)o[6] | ((u32)o[7] << 16);
    *(uint4*)(dst + (size_t)head * 256 * 64 + ((size_t)f * 64 + lane) * 8) = v;
}

// ---------- pack gate w2[256] -> column-broadcast frags (8 frags/head, sH perm) ----------
__global__ void k_packg(const float* __restrict__ src, u16* __restrict__ dst, int nheads)
{
    const int t = blockIdx.x * 256 + threadIdx.x;
    if (t >= nheads * 8 * 64) return;
    const int lane = t & 63;
    const int fh = t >> 6;
    const int f = fh & 7, head = fh >> 3;
    const int half = f >> 2, k2l = f & 3;
    const int q = lane >> 4;
    u16 o[8];
    #pragma unroll
    for (int i = 0; i < 8; ++i) {
        const int pl = 32 * k2l + 8 * q + i;
        const int krow = (pl >> 5) * 64 + (2 * half + (pl & 1)) * 16 + ((pl >> 1) & 15);
        o[i] = f2bf(src[head * 256 + krow]);
    }
    uint4 v;
    v.x = (u32)o[0] | ((u32)o[1] << 16);
    v.y = (u32)o[2] | ((u32)o[3] << 16);
    v.z = (u32)o[4] | ((u32)o[5] << 16);
    v.w = (u32)o[6] | ((u32)o[7] << 16);
    *(uint4*)(dst + ((size_t)(head * 8 + f) * 64 + lane) * 8) = v;
}

// ---------- embedding as MFMA GEMM ----------
__global__ __launch_bounds__(256) void k_embed_mm(
    const float* __restrict__ elem_fea, const float* __restrict__ elem_w,
    const u16* __restrict__ webp, const float* __restrict__ emb_b,
    float* __restrict__ x, u16* __restrict__ xbf)
{
    __shared__ __align__(16) u16 Ahi[64 * 256];
    __shared__ __align__(16) u16 Alo[64 * 256];
    const int tid = threadIdx.x;
    const int n0 = blockIdx.x * 64;

    for (int i = tid; i < 64 * 3; i += 256) {
        const int row = i / 3, j = 25 + i % 3;
        uint4 z; z.x = 0; z.y = 0; z.z = 0; z.w = 0;
        *(uint4*)((char*)Ahi + row * 512 + ((j ^ (row & 7)) * 16)) = z;
        *(uint4*)((char*)Alo + row * 512 + ((j ^ (row & 7)) * 16)) = z;
    }
    for (int i = tid; i < 64 * 50; i += 256) {
        const int row = i / 50, f4 = i % 50;
        const int node = min(n0 + row, NN - 1);
        float4 v = *(const float4*)(elem_fea + (size_t)node * EMBD + f4 * 4);
        const u16 h0 = f2bf(v.x), h1 = f2bf(v.y), h2 = f2bf(v.z), h3 = f2bf(v.w);
        uint2 hi, lo;
        hi.x = (u32)h0 | ((u32)h1 << 16);
        hi.y = (u32)h2 | ((u32)h3 << 16);
        lo.x = (u32)f2bf(v.x - bf2f(h0)) | ((u32)f2bf(v.y - bf2f(h1)) << 16);
        lo.y = (u32)f2bf(v.z - bf2f(h2)) | ((u32)f2bf(v.w - bf2f(h3)) << 16);
        const int off = row * 512 + (((f4 >> 1) ^ (row & 7)) * 16) + (f4 & 1) * 8;
        *(uint2*)((char*)Ahi + off) = hi;
        *(uint2*)((char*)Alo + off) = lo;
    }
    __syncthreads();

    const int w = tid >> 6, lane = tid & 63, q = lane >> 4, c = lane & 15;
    s16x8 B[7];
    #pragma unroll
    for (int ks = 0; ks < 7; ++ks)
        B[ks] = *(const s16x8*)(webp + ((size_t)(ks * 4 + w) * 64 + lane) * 8);
    f32x4 acc[4];
    #pragma unroll
    for (int m = 0; m < 4; ++m) acc[m] = 0.f;
    #pragma unroll
    for (int ks = 0; ks < 7; ++ks) {
        #pragma unroll
        for (int m = 0; m < 4; ++m) {
            const int row = m * 16 + c;
            const int g = (ks * 4 + q) ^ (row & 7);
            s16x8 ah = *(const s16x8*)((const char*)Ahi + row * 512 + g * 16);
            s16x8 al = *(const s16x8*)((const char*)Alo + row * 512 + g * 16);
            acc[m] = __builtin_amdgcn_mfma_f32_16x16x32_bf16(ah, B[ks], acc[m], 0, 0, 0);
            acc[m] = __builtin_amdgcn_mfma_f32_16x16x32_bf16(al, B[ks], acc[m], 0, 0, 0);
        }
    }
    const int col = w * 16 + c;
    const float bv = (col < 63) ? emb_b[col] : 0.f;
    #pragma unroll
    for (int m = 0; m < 4; ++m)
        #pragma unroll
        for (int r = 0; r < 4; ++r) {
            const int node = n0 + m * 16 + q * 4 + r;
            if (node < NN) {
                const float val = (col < 63) ? acc[m][r] + bv : elem_w[node];
                x[(size_t)node * 64 + col] = val;
                xbf[(size_t)node * 64 + col] = f2bf(val);
            }
        }
}

// ================= CSR build (generic over segments) =================
__global__ void k_deg(const int* __restrict__ idx, int* __restrict__ deg, int n) {
    int e = blockIdx.x * 256 + threadIdx.x;
    if (e < n) atomicAdd(&deg[idx[e]], 1);
}

__global__ void k_nodepack(const int* __restrict__ deg, int* __restrict__ nstart,
                           int* __restrict__ ctotal, int total_n)
{
    __shared__ int sdeg[1024];
    __shared__ int sst[1024];
    const int c0 = blockIdx.x << 10;
    const int cnt = min(1024, total_n - c0);
    for (int i = threadIdx.x; i < cnt; i += 64) sdeg[i] = deg[c0 + i];
    __syncthreads();
    if (threadIdx.x == 0) {
        int cur = 0;
        for (int i = 0; i < cnt; ++i) {
            int d = sdeg[i];
            if (d > 0 && ((cur & 63) + d > 64)) cur = (cur + 63) & ~63;
            sst[i] = cur;
            cur += d;
        }
        ctotal[blockIdx.x] = (cur + 63) & ~63;
    }
    __syncthreads();
    for (int i = threadIdx.x; i < cnt; i += 64) nstart[c0 + i] = sst[i];
}

__global__ void k_chunkscan(const int* __restrict__ ctotal, int* __restrict__ cbase, int nch) {
    __shared__ int s[256];
    int t = threadIdx.x;
    int v = (t < nch) ? ctotal[t] : 0;
    s[t] = v;
    __syncthreads();
    for (int off = 1; off < 256; off <<= 1) {
        int add = (t >= off) ? s[t - off] : 0;
        __syncthreads();
        s[t] += add;
        __syncthreads();
    }
    if (t < nch) cbase[t] = s[t] - v;
}

// edge fill: gnode[slot]=(self,nbr), gwn[slot]=elem_w[nbr]
__global__ void k_fill(const int* __restrict__ self_idx, const int* __restrict__ nbr_idx,
                       const float* __restrict__ elem_w,
                       const int* __restrict__ nstart, const int* __restrict__ cbase,
                       int* __restrict__ cursor, int2* __restrict__ gnode,
                       float* __restrict__ gwn)
{
    int e = blockIdx.x * 256 + threadIdx.x;
    if (e >= NE) return;
    int n = self_idx[e];
    int r = atomicAdd(&cursor[n], 1);
    int slot = cbase[n >> 10] + nstart[n] + r;
    int nb = nbr_idx[e];
    gnode[slot] = make_int2(n, nb);
    gwn[slot] = elem_w[nb];
}

// crystal fill: cgnode[slot]=(crystal,node), cgwn[slot]=elem_w[node]
__global__ void k_cfill(const int* __restrict__ cry_idx, const float* __restrict__ elem_w,
                        const int* __restrict__ nstart, const int* __restrict__ cbase,
                        int* __restrict__ cursor, int2* __restrict__ gnode,
                        float* __restrict__ gwn)
{
    int n = blockIdx.x * 256 + threadIdx.x;
    if (n >= NN) return;
    int cg = cry_idx[n];
    int r = atomicAdd(&cursor[cg], 1);
    int slot = cbase[cg >> 10] + nstart[cg] + r;
    gnode[slot] = make_int2(cg, n);
    gwn[slot] = elem_w[n];
}

// ================= gate: full-width GEMM1 acc[4][4] + MFMA w2-reduction + softmax ======
template<int KD>
__global__ __launch_bounds__(256, 3) void k_lgate(
    const u16* __restrict__ xbf, const int2* __restrict__ gnode,
    const float* __restrict__ gwn,
    const u16* __restrict__ gw1p, const float* __restrict__ gb1,
    const u16* __restrict__ gw2p, const float* __restrict__ gpw,
    float* __restrict__ sgf_out, size_t sstr)
{
    constexpr int KS = KD / 32;
    constexpr int G  = KD / 8;
    constexpr int RB = KD * 2;
    __shared__ __align__(16) u16 sA[64 * KD];
    __shared__ __align__(16) u16 sH[64 * 128];
    __shared__ float sg[4][64];
    __shared__ float gfin[64], tval[64];
    __shared__ float swn[64];
    __shared__ int   snid[64];
    __shared__ short srs[64], sre[64];
    const int tid = threadIdx.x;
    const int base = blockIdx.x * 64;
    if (gnode[base].x < 0) return;

    if (tid < 64) {
        int2 nn = gnode[base + tid];
        snid[tid] = nn.x;
        swn[tid] = gwn[base + tid];
    }
    for (int i = tid; i < 64 * G; i += 256) {
        const int row = i / G, g = i % G;
        const int2 nn = gnode[base + row];
        const int node = (KD == 128) ? ((g < 8) ? nn.x : nn.y) : nn.y;
        uint4 v; v.x = 0; v.y = 0; v.z = 0; v.w = 0;
        if (node >= 0) v = *(const uint4*)(xbf + (size_t)node * 64 + (g & 7) * 8);
        *(uint4*)((char*)sA + row * RB + ((g ^ (row & 7)) * 16)) = v;
    }
    __syncthreads();
    if (tid < 64) {
        int n = snid[tid];
        int rs = tid, re = tid + 1;
        if (n >= 0) {
            while (rs > 0 && snid[rs - 1] == n) --rs;
            while (re < 64 && snid[re] == n) ++re;
        }
        srs[tid] = (short)rs; sre[tid] = (short)re;
    }

    const int w = tid >> 6, lane = tid & 63, q = lane >> 4, c = lane & 15;

    #pragma unroll 1
    for (int h = 0; h < 3; ++h) {
        const u16* wp = gw1p + (size_t)h * KD * 256;
        // GEMM1 full-width: single pass over sA, acc[4][4]
        f32x4 acc[4][4];
        #pragma unroll
        for (int m = 0; m < 4; ++m)
            #pragma unroll
            for (int n4 = 0; n4 < 4; ++n4) acc[m][n4] = 0.f;
        __builtin_amdgcn_s_setprio(1);
        #pragma unroll 2
        for (int ks = 0; ks < KS; ++ks) {
            s16x8 a[4];
            #pragma unroll
            for (int m = 0; m < 4; ++m) {
                const int row = m * 16 + c;
                a[m] = *(const s16x8*)((const char*)sA + row * RB + (((ks * 4 + q) ^ (row & 7)) * 16));
            }
            #pragma unroll
            for (int n4 = 0; n4 < 4; ++n4) {
                s16x8 B1 = *(const s16x8*)(wp + ((size_t)(ks * 16 + w * 4 + n4) * 64 + lane) * 8);
                #pragma unroll
                for (int m = 0; m < 4; ++m)
                    acc[m][n4] = __builtin_amdgcn_mfma_f32_16x16x32_bf16(a[m], B1, acc[m][n4], 0, 0, 0);
            }
        }
        __builtin_amdgcn_s_setprio(0);

        f32x4 acc2[4];
        #pragma unroll
        for (int m = 0; m < 4; ++m) acc2[m] = 0.f;
        #pragma unroll 1
        for (int h2 = 0; h2 < 2; ++h2) {
            __syncthreads();   // prev sH consumers done
            const float b1a = gb1[h * 256 + w * 64 + (h2 * 2 + 0) * 16 + c];
            const float b1b = gb1[h * 256 + w * 64 + (h2 * 2 + 1) * 16 + c];
            #pragma unroll
            for (int m = 0; m < 4; ++m)
                #pragma unroll
                for (int r = 0; r < 4; ++r) {
                    const int row = m * 16 + q * 4 + r;
                    const u32 pk = cvtpk(lrelu(acc[m][h2 * 2 + 0][r] + b1a),
                                         lrelu(acc[m][h2 * 2 + 1][r] + b1b));
                    *(u32*)((char*)sH + row * 256 + (((w * 4 + (c >> 2)) ^ (row & 7)) * 16) + (c & 3) * 4) = pk;
                }
            s16x8 B2 = *(const s16x8*)(gw2p + ((size_t)(h * 8 + h2 * 4 + w) * 64 + lane) * 8);
            __syncthreads();

            __builtin_amdgcn_s_setprio(1);
            #pragma unroll
            for (int m = 0; m < 4; ++m) {
                const int row = m * 16 + c;
                s16x8 a2 = *(const s16x8*)((const char*)sH + row * 256 + (((w * 4 + q) ^ (row & 7)) * 16));
                acc2[m] = __builtin_amdgcn_mfma_f32_16x16x32_bf16(a2, B2, acc2[m], 0, 0, 0);
            }
            __builtin_amdgcn_s_setprio(0);
        }
        if (c == 0) {
            #pragma unroll
            for (int m = 0; m < 4; ++m)
                #pragma unroll
                for (int r = 0; r < 4; ++r)
                    sg[w][m * 16 + q * 4 + r] = acc2[m][r];
        }
        __syncthreads();
        if (tid < 64)
            gfin[tid] = (snid[tid] >= 0) ? sg[0][tid] + sg[1][tid] + sg[2][tid] + sg[3][tid] : -1e30f;
        __syncthreads();
        if (tid < 64) {
            const int rs = srs[tid], re = sre[tid];
            float m = -1e30f;
            for (int j = rs; j < re; ++j) m = fmaxf(m, gfin[j]);
            tval[tid] = (snid[tid] >= 0) ? powf(swn[tid], gpw[h]) * expf(gfin[tid] - m) : 0.f;
        }
        __syncthreads();
        if (tid < 64) {
            const int rs = srs[tid], re = sre[tid];
            float d = 1e-10f;
            for (int j = rs; j < re; ++j) d += tval[j];
            sgf_out[sstr * h + base + tid] = tval[tid] / d;
        }
        __syncthreads();
    }
}

// ================= msg: full-width GEMM1 acc[4][4] + GEMM2 + block-local pooling =======
template<int KD, bool RESID>
__global__ __launch_bounds__(256, 3) void k_lmsg(
    const u16* __restrict__ xbf, const int2* __restrict__ gnode,
    const u16* __restrict__ mw1p, const float* __restrict__ mb1,
    const u16* __restrict__ mw2p, const float* __restrict__ mb2,
    const float* __restrict__ sgf_in, float* __restrict__ outp, size_t sstr)
{
    constexpr int KS = KD / 32;
    constexpr int G  = KD / 8;
    constexpr int RB = KD * 2;
    __shared__ __align__(16) u16 sA[64 * KD];
    __shared__ __align__(16) u16 sH[64 * 128];
    __shared__ float sgfl[64][3];
    __shared__ int   snid[64];
    __shared__ short srs[64], sre[64];
    const int tid = threadIdx.x;
    const int base = blockIdx.x * 64;
    if (gnode[base].x < 0) return;

    if (tid < 64) snid[tid] = gnode[base + tid].x;
    if (tid < 192) {
        const int row = tid / 3, h = tid % 3;
        sgfl[row][h] = sgf_in[sstr * h + base + row];
    }
    for (int i = tid; i < 64 * G; i += 256) {
        const int row = i / G, g = i % G;
        const int2 nn = gnode[base + row];
        const int node = (KD == 128) ? ((g < 8) ? nn.x : nn.y) : nn.y;
        uint4 v; v.x = 0; v.y = 0; v.z = 0; v.w = 0;
        if (node >= 0) v = *(const uint4*)(xbf + (size_t)node * 64 + (g & 7) * 8);
        *(uint4*)((char*)sA + row * RB + ((g ^ (row & 7)) * 16)) = v;
    }
    __syncthreads();
    if (tid < 64) {
        int n = snid[tid];
        int rs = tid, re = tid + 1;
        if (n >= 0) {
            while (rs > 0 && snid[rs - 1] == n) --rs;
            while (re < 64 && snid[re] == n) ++re;
        }
        srs[tid] = (short)rs; sre[tid] = (short)re;
    }

    const int w = tid >> 6, lane = tid & 63, q = lane >> 4, c = lane & 15;
    float wacc[4][4];
    #pragma unroll
    for (int m = 0; m < 4; ++m)
        #pragma unroll
        for (int r = 0; r < 4; ++r) wacc[m][r] = 0.f;

    #pragma unroll 1
    for (int h = 0; h < 3; ++h) {
        const u16* wp = mw1p + (size_t)h * KD * 256;
        // GEMM1 full-width: single pass over sA, acc[4][4]
        f32x4 acc[4][4];
        #pragma unroll
        for (int m = 0; m < 4; ++m)
            #pragma unroll
            for (int n4 = 0; n4 < 4; ++n4) acc[m][n4] = 0.f;
        __builtin_amdgcn_s_setprio(1);
        #pragma unroll 2
        for (int ks = 0; ks < KS; ++ks) {
            s16x8 a[4];
            #pragma unroll
            for (int m = 0; m < 4; ++m) {
                const int row = m * 16 + c;
                a[m] = *(const s16x8*)((const char*)sA + row * RB + (((ks * 4 + q) ^ (row & 7)) * 16));
            }
            #pragma unroll
            for (int n4 = 0; n4 < 4; ++n4) {
                s16x8 B1 = *(const s16x8*)(wp + ((size_t)(ks * 16 + w * 4 + n4) * 64 + lane) * 8);
                #pragma unroll
                for (int m = 0; m < 4; ++m)
                    acc[m][n4] = __builtin_amdgcn_mfma_f32_16x16x32_bf16(a[m], B1, acc[m][n4], 0, 0, 0);
            }
        }
        __builtin_amdgcn_s_setprio(0);

        #pragma unroll 1
        for (int h2 = 0; h2 < 2; ++h2) {
            __syncthreads();   // prev sH consumers done
            const float b1a = mb1[h * 256 + w * 64 + (h2 * 2 + 0) * 16 + c];
            const float b1b = mb1[h * 256 + w * 64 + (h2 * 2 + 1) * 16 + c];
            #pragma unroll
            for (int m = 0; m < 4; ++m)
                #pragma unroll
                for (int r = 0; r < 4; ++r) {
                    const int row = m * 16 + q * 4 + r;
                    const u32 pk = cvtpk(lrelu(acc[m][h2 * 2 + 0][r] + b1a),
                                         lrelu(acc[m][h2 * 2 + 1][r] + b1b));
                    *(u32*)((char*)sH + row * 256 + (((w * 4 + (c >> 2)) ^ (row & 7)) * 16) + (c & 3) * 4) = pk;
                }
            s16x8 B2[4];
            #pragma unroll
            for (int k2 = 0; k2 < 4; ++k2)
                B2[k2] = *(const s16x8*)(mw2p + (size_t)h * 256 * 64 + ((size_t)((h2 * 4 + k2) * 4 + w) * 64 + lane) * 8);
            __syncthreads();

            f32x4 acc2[4];
            #pragma unroll
            for (int m = 0; m < 4; ++m) acc2[m] = 0.f;
            __builtin_amdgcn_s_setprio(1);
            #pragma unroll
            for (int k2 = 0; k2 < 4; ++k2) {
                #pragma unroll
                for (int m2 = 0; m2 < 4; ++m2) {
                    const int row = m2 * 16 + c;
                    s16x8 a2 = *(const s16x8*)((const char*)sH + row * 256 + (((k2 * 4 + q) ^ (row & 7)) * 16));
                    acc2[m2] = __builtin_amdgcn_mfma_f32_16x16x32_bf16(a2, B2[k2], acc2[m2], 0, 0, 0);
                }
            }
            __builtin_amdgcn_s_setprio(0);
            const float b2v = h2 ? mb2[h * 64 + w * 16 + c] : 0.f;
            #pragma unroll
            for (int m2 = 0; m2 < 4; ++m2)
                #pragma unroll
                for (int r = 0; r < 4; ++r) {
                    const int row = m2 * 16 + q * 4 + r;
                    wacc[m2][r] += (acc2[m2][r] + b2v) * sgfl[row][h];
                }
        }
    }
    __syncthreads();

    float* waccL = (float*)sH;
    #pragma unroll
    for (int m = 0; m < 4; ++m)
        #pragma unroll
        for (int r = 0; r < 4; ++r)
            waccL[(m * 16 + q * 4 + r) * 64 + w * 16 + c] = wacc[m][r];
    __syncthreads();
    {
        const int col = tid & 63, grp = tid >> 6;
        for (int i = grp; i < 64; i += 4) {
            const int n = snid[i];
            if (n >= 0 && srs[i] == (short)i) {
                float s = 0.f;
                const int re = sre[i];
                for (int j = i; j < re; ++j) s += waccL[j * 64 + col];
                if (RESID) outp[(size_t)n * 64 + col] += s * (1.f / 3.f);
                else       outp[(size_t)n * 64 + col]  = s * (1.f / 3.f);
            }
        }
    }
}

// ---------- refresh bf16 mirror (x read-only) ----------
__global__ void k_mirror(const float* __restrict__ x, u16* __restrict__ xbf, int n4)
{
    int i = blockIdx.x * 256 + threadIdx.x;
    if (i >= n4) return;
    float4 xv = *(const float4*)(x + (size_t)i * 4);
    uint2 o;
    o.x = cvtpk(xv.x, xv.y);
    o.y = cvtpk(xv.z, xv.w);
    *(uint2*)(xbf + (size_t)i * 4) = o;
}

extern "C" void kernel_launch(void* const* d_in, const int* in_sizes, int n_in,
                              void* d_out, int out_size, void* d_ws, size_t ws_size,
                              hipStream_t stream)
{
    const float* elem_w   = (const float*)d_in[0];
    const float* elem_fea = (const float*)d_in[1];
    const int*   self_idx = (const int*)d_in[2];
    const int*   nbr_idx  = (const int*)d_in[3];
    const int*   cry_idx  = (const int*)d_in[4];
    const float* emb_w    = (const float*)d_in[5];
    const float* emb_b    = (const float*)d_in[6];
    const float* gg_w1    = (const float*)d_in[7];
    const float* gg_b1    = (const float*)d_in[8];
    const float* gg_w2    = (const float*)d_in[9];
    const float* gm_w1    = (const float*)d_in[11];
    const float* gm_b1    = (const float*)d_in[12];
    const float* gm_w2    = (const float*)d_in[13];
    const float* gm_b2    = (const float*)d_in[14];
    const float* g_pow    = (const float*)d_in[15];
    const float* cg_w1    = (const float*)d_in[16];
    const float* cg_b1    = (const float*)d_in[17];
    const float* cg_w2    = (const float*)d_in[18];
    const float* cm_w1    = (const float*)d_in[20];
    const float* cm_b1    = (const float*)d_in[21];
    const float* cm_w2    = (const float*)d_in[22];
    const float* cm_b2    = (const float*)d_in[23];
    const float* c_pow    = (const float*)d_in[24];

    char* wsp = (char*)d_ws;
    size_t off = 0;
    auto alloc = [&](size_t b) { char* p = wsp + off; off += (b + 255) & ~(size_t)255; return p; };
    float* x      = (float*)alloc((size_t)NN * 64 * 4);
    u16*   xbf    = (u16*)  alloc((size_t)NN * 64 * 2);
    float* sgf    = (float*)alloc((size_t)3 * SSTR * 4);
    float* csgf   = (float*)alloc((size_t)3 * SSTRC * 4);
    int* deg    = (int*)alloc((size_t)NN * 4);
    int* nstart = (int*)alloc((size_t)NN * 4);
    int* cursor = (int*)alloc((size_t)NN * 4);
    int* ctotal = (int*)alloc((size_t)NCH_E * 4);
    int* cbase  = (int*)alloc((size_t)NCH_E * 4);
    int2* gnode = (int2*)alloc((size_t)NBLK * 64 * 8);
    float* gwn  = (float*)alloc((size_t)NBLK * 64 * 4);
    int* cdeg    = (int*)alloc((size_t)NC * 4);
    int* cnstart = (int*)alloc((size_t)NC * 4);
    int* ccursor = (int*)alloc((size_t)NC * 4);
    int* cctotal = (int*)alloc((size_t)NCH_C * 4);
    int* ccbase  = (int*)alloc((size_t)NCH_C * 4);
    int2* cgnode = (int2*)alloc((size_t)NCBLK * 64 * 8);
    float* cgwn  = (float*)alloc((size_t)NCBLK * 64 * 4);
    u16* wg1p = (u16*)alloc((size_t)9 * 128 * 256 * 2);
    u16* wm1p = (u16*)alloc((size_t)9 * 128 * 256 * 2);
    u16* wm2p = (u16*)alloc((size_t)9 * 256 * 64 * 2);
    u16* wg2p = (u16*)alloc((size_t)9 * 8 * 64 * 8 * 2);
    u16* cg1p = (u16*)alloc((size_t)3 * 64 * 256 * 2);
    u16* cm1p = (u16*)alloc((size_t)3 * 64 * 256 * 2);
    u16* cm2p = (u16*)alloc((size_t)3 * 256 * 64 * 2);
    u16* cg2p = (u16*)alloc((size_t)3 * 8 * 64 * 8 * 2);
    u16* webp = (u16*)alloc((size_t)224 * 64 * 2);

    auto pack = [&](const float* s, u16* d, int K, int N, int H) {
        int tot = H * (K / 32) * (N / 16) * 64;
        k_pack<<<(tot + 255) / 256, 256, 0, stream>>>(s, d, K, N, H);
    };
    pack(gg_w1, wg1p, 128, 256, 9);
    pack(gm_w1, wm1p, 128, 256, 9);
    pack(cg_w1, cg1p, 64, 256, 3);
    pack(cm_w1, cm1p, 64, 256, 3);
    k_pack2<<<(9 * 32 * 64 + 255) / 256, 256, 0, stream>>>(gm_w2, wm2p, 9);
    k_pack2<<<(3 * 32 * 64 + 255) / 256, 256, 0, stream>>>(cm_w2, cm2p, 3);
    k_packg<<<(9 * 8 * 64 + 255) / 256, 256, 0, stream>>>(gg_w2, wg2p, 9);
    k_packg<<<(3 * 8 * 64 + 255) / 256, 256, 0, stream>>>(cg_w2, cg2p, 3);
    k_packe<<<7, 256, 0, stream>>>(emb_w, webp);

    // edge CSR
    hipMemsetAsync(deg, 0, (size_t)NN * 4, stream);
    hipMemsetAsync(cursor, 0, (size_t)NN * 4, stream);
    hipMemsetAsync(gnode, 0xFF, (size_t)NBLK * 64 * 8, stream);
    k_deg<<<(NE + 255) / 256, 256, 0, stream>>>(self_idx, deg, NE);
    k_nodepack<<<NCH_E, 64, 0, stream>>>(deg, nstart, ctotal, NN);
    k_chunkscan<<<1, 256, 0, stream>>>(ctotal, cbase, NCH_E);
    k_fill<<<(NE + 255) / 256, 256, 0, stream>>>(self_idx, nbr_idx, elem_w,
                                                 nstart, cbase, cursor, gnode, gwn);
    // crystal CSR
    hipMemsetAsync(cdeg, 0, (size_t)NC * 4, stream);
    hipMemsetAsync(ccursor, 0, (size_t)NC * 4, stream);
    hipMemsetAsync(cgnode, 0xFF, (size_t)NCBLK * 64 * 8, stream);
    k_deg<<<(NN + 255) / 256, 256, 0, stream>>>(cry_idx, cdeg, NN);
    k_nodepack<<<NCH_C, 64, 0, stream>>>(cdeg, cnstart, cctotal, NC);
    k_chunkscan<<<1, 256, 0, stream>>>(cctotal, ccbase, NCH_C);
    k_cfill<<<(NN + 255) / 256, 256, 0, stream>>>(cry_idx, elem_w,
                                                  cnstart, ccbase, ccursor, cgnode, cgwn);

    k_embed_mm<<<(NN + 63) / 64, 256, 0, stream>>>(elem_fea, elem_w, webp, emb_b, x, xbf);

    for (int l = 0; l < 3; ++l) {
        k_lgate<128><<<NBLK, 256, 0, stream>>>(
            xbf, gnode, gwn,
            wg1p + (size_t)l * 3 * 128 * 256, gg_b1 + l * 768,
            wg2p + (size_t)l * 3 * 8 * 64 * 8, g_pow + l * 3, sgf, SSTR);
        k_lmsg<128, true><<<NBLK, 256, 0, stream>>>(
            xbf, gnode,
            wm1p + (size_t)l * 3 * 128 * 256, gm_b1 + l * 768,
            wm2p + (size_t)l * 3 * 256 * 64, gm_b2 + l * 192, sgf, x, SSTR);
        k_mirror<<<(NN * 64 / 4 + 255) / 256, 256, 0, stream>>>(x, xbf, NN * 64 / 4);
    }

    hipMemsetAsync(d_out, 0, (size_t)NC * 64 * 4, stream);
    k_lgate<64><<<NCBLK, 256, 0, stream>>>(
        xbf, cgnode, cgwn, cg1p, cg_b1, cg2p, c_pow, csgf, SSTRC);
    k_lmsg<64, false><<<NCBLK, 256, 0, stream>>>(
        xbf, cgnode, cm1p, cm_b1, cm2p, cm_b2, csgf, (float*)d_out, SSTRC);
}

// Round 16
// 3986.934 us; speedup vs baseline: 2.4208x; 2.4208x over previous
//
#include <hip/hip_runtime.h>
#include <math.h>

#define NN 250000
#define NE 1250000
#define NC 50000
#define EMBD 200
#define NCH 245          // ceil(NN/1024) node chunks for CSR packing
#define NBLK 22000       // edge-slot blocks (64 slots each)
#define SSTR ((size_t)NBLK * 64)   // sgf planar stride

typedef unsigned int u32;
typedef unsigned short u16;
typedef short s16x8 __attribute__((ext_vector_type(8)));
typedef float f32x4 __attribute__((ext_vector_type(4)));

__device__ __forceinline__ u16 f2bf(float f) {
    u32 u = __float_as_uint(f);
    return (u16)((u + 0x7FFFu + ((u >> 16) & 1u)) >> 16);   // RNE
}
__device__ __forceinline__ float bf2f(u16 u) { return __uint_as_float(((u32)u) << 16); }
__device__ __forceinline__ u32 cvtpk(float lo, float hi) {
    u32 r;
    asm("v_cvt_pk_bf16_f32 %0, %1, %2" : "=v"(r) : "v"(lo), "v"(hi));
    return r;
}
__device__ __forceinline__ float lrelu(float v) { return v > 0.f ? v : 0.01f * v; }
__device__ __forceinline__ u32 encf(float f) {
    u32 u = __float_as_uint(f);
    return (u & 0x80000000u) ? ~u : (u | 0x80000000u);
}
__device__ __forceinline__ float decf(u32 k) {
    return __uint_as_float((k & 0x80000000u) ? (k ^ 0x80000000u) : ~k);
}

// ---------- pack W[K][N] f32 -> fragment-major bf16 (B-operand, mfma_16x16x32) ----------
__global__ void k_pack(const float* __restrict__ src, u16* __restrict__ dst,
                       int K, int N, int nheads)
{
    const int t = blockIdx.x * 256 + threadIdx.x;
    const int F = (K / 32) * (N / 16);
    if (t >= nheads * F * 64) return;
    const int lane = t & 63;
    const int fh = t >> 6;
    const int f = fh % F, head = fh / F;
    const int ng = f % (N / 16), ks = f / (N / 16);
    const int q = lane >> 4, c = lane & 15;
    const float* s = src + (size_t)head * K * N;
    u16 o[8];
    #pragma unroll
    for (int i = 0; i < 8; ++i)
        o[i] = f2bf(s[(size_t)(32 * ks + 8 * q + i) * N + 16 * ng + c]);
    uint4 v;
    v.x = (u32)o[0] | ((u32)o[1] << 16);
    v.y = (u32)o[2] | ((u32)o[3] << 16);
    v.z = (u32)o[4] | ((u32)o[5] << 16);
    v.w = (u32)o[6] | ((u32)o[7] << 16);
    *(uint4*)(dst + (size_t)head * K * N + ((size_t)f * 64 + lane) * 8) = v;
}

// ---------- pack emb_w [200][63] -> frag-major bf16, K=224 N=64, zero-padded ----------
__global__ void k_packe(const float* __restrict__ src, u16* __restrict__ dst)
{
    const int t = blockIdx.x * 256 + threadIdx.x;
    if (t >= 28 * 64) return;
    const int lane = t & 63, f = t >> 6;
    const int ng = f & 3, ks = f >> 2;
    const int q = lane >> 4, c = lane & 15;
    u16 o[8];
    #pragma unroll
    for (int i = 0; i < 8; ++i) {
        const int kr = 32 * ks + 8 * q + i;
        const int col = 16 * ng + c;
        o[i] = (kr < EMBD && col < 63) ? f2bf(src[kr * 63 + col]) : (u16)0;
    }
    uint4 v;
    v.x = (u32)o[0] | ((u32)o[1] << 16);
    v.y = (u32)o[2] | ((u32)o[3] << 16);
    v.z = (u32)o[4] | ((u32)o[5] << 16);
    v.w = (u32)o[6] | ((u32)o[7] << 16);
    *(uint4*)(dst + ((size_t)f * 64 + lane) * 8) = v;
}

// ---------- pack W2[256][64] with the sH permutation ----------
__global__ void k_pack2(const float* __restrict__ src, u16* __restrict__ dst, int nheads)
{
    const int t = blockIdx.x * 256 + threadIdx.x;
    const int F = 32;
    if (t >= nheads * F * 64) return;
    const int lane = t & 63;
    const int fh = t >> 6;
    const int f = fh % F, head = fh / F;
    const int ks2 = f >> 2, ng = f & 3;
    const int q = lane >> 4, c = lane & 15;
    const int half = ks2 >> 2, k2l = ks2 & 3;
    const float* s = src + (size_t)head * 256 * 64;
    u16 o[8];
    #pragma unroll
    for (int i = 0; i < 8; ++i) {
        const int pl = 32 * k2l + 8 * q + i;
        const int krow = (pl >> 5) * 64 + (2 * half + (pl & 1)) * 16 + ((pl >> 1) & 15);
        o[i] = f2bf(s[(size_t)krow * 64 + 16 * ng + c]);
    }
    uint4 v;
    v.x = (u32)o[0] | ((u32)o[1] << 16);
    v.y = (u32)o[2] | ((u32)o[3] << 16);
    v.z = (u32)o[4] | ((u32)o[5] << 16);
    v.w = (u32)o[6] | ((u32)o[7] << 16);
    *(uint4*)(dst + (size_t)head * 256 * 64 + ((size_t)f * 64 + lane) * 8) = v;
}

// ---------- pack gate w2[256] -> column-broadcast frags with sH permutation ----------
__global__ void k_packg(const float* __restrict__ src, u16* __restrict__ dst, int nheads)
{
    const int t = blockIdx.x * 256 + threadIdx.x;
    if (t >= nheads * 8 * 64) return;
    const int lane = t & 63;
    const int fh = t >> 6;
    const int f = fh & 7, head = fh >> 3;
    const int half = f >> 2, k2l = f & 3;
    const int q = lane >> 4;
    u16 o[8];
    #pragma unroll
    for (int i = 0; i < 8; ++i) {
        const int pl = 32 * k2l + 8 * q + i;
        const int krow = (pl >> 5) * 64 + (2 * half + (pl & 1)) * 16 + ((pl >> 1) & 15);
        o[i] = f2bf(src[head * 256 + krow]);
    }
    uint4 v;
    v.x = (u32)o[0] | ((u32)o[1] << 16);
    v.y = (u32)o[2] | ((u32)o[3] << 16);
    v.z = (u32)o[4] | ((u32)o[5] << 16);
    v.w = (u32)o[6] | ((u32)o[7] << 16);
    *(uint4*)(dst + ((size_t)(head * 8 + f) * 64 + lane) * 8) = v;
}

// ---------- embedding as MFMA GEMM ----------
__global__ __launch_bounds__(256) void k_embed_mm(
    const float* __restrict__ elem_fea, const float* __restrict__ elem_w,
    const u16* __restrict__ webp, const float* __restrict__ emb_b,
    float* __restrict__ x, u16* __restrict__ xbf)
{
    __shared__ __align__(16) u16 Ahi[64 * 256];
    __shared__ __align__(16) u16 Alo[64 * 256];
    const int tid = threadIdx.x;
    const int n0 = blockIdx.x * 64;

    for (int i = tid; i < 64 * 3; i += 256) {
        const int row = i / 3, j = 25 + i % 3;
        uint4 z; z.x = 0; z.y = 0; z.z = 0; z.w = 0;
        *(uint4*)((char*)Ahi + row * 512 + ((j ^ (row & 7)) * 16)) = z;
        *(uint4*)((char*)Alo + row * 512 + ((j ^ (row & 7)) * 16)) = z;
    }
    for (int i = tid; i < 64 * 50; i += 256) {
        const int row = i / 50, f4 = i % 50;
        const int node = min(n0 + row, NN - 1);
        float4 v = *(const float4*)(elem_fea + (size_t)node * EMBD + f4 * 4);
        const u16 h0 = f2bf(v.x), h1 = f2bf(v.y), h2 = f2bf(v.z), h3 = f2bf(v.w);
        uint2 hi, lo;
        hi.x = (u32)h0 | ((u32)h1 << 16);
        hi.y = (u32)h2 | ((u32)h3 << 16);
        lo.x = (u32)f2bf(v.x - bf2f(h0)) | ((u32)f2bf(v.y - bf2f(h1)) << 16);
        lo.y = (u32)f2bf(v.z - bf2f(h2)) | ((u32)f2bf(v.w - bf2f(h3)) << 16);
        const int off = row * 512 + (((f4 >> 1) ^ (row & 7)) * 16) + (f4 & 1) * 8;
        *(uint2*)((char*)Ahi + off) = hi;
        *(uint2*)((char*)Alo + off) = lo;
    }
    __syncthreads();

    const int w = tid >> 6, lane = tid & 63, q = lane >> 4, c = lane & 15;
    s16x8 B[7];
    #pragma unroll
    for (int ks = 0; ks < 7; ++ks)
        B[ks] = *(const s16x8*)(webp + ((size_t)(ks * 4 + w) * 64 + lane) * 8);
    f32x4 acc[4];
    #pragma unroll
    for (int m = 0; m < 4; ++m) acc[m] = 0.f;
    #pragma unroll
    for (int ks = 0; ks < 7; ++ks) {
        #pragma unroll
        for (int m = 0; m < 4; ++m) {
            const int row = m * 16 + c;
            const int g = (ks * 4 + q) ^ (row & 7);
            s16x8 ah = *(const s16x8*)((const char*)Ahi + row * 512 + g * 16);
            s16x8 al = *(const s16x8*)((const char*)Alo + row * 512 + g * 16);
            acc[m] = __builtin_amdgcn_mfma_f32_16x16x32_bf16(ah, B[ks], acc[m], 0, 0, 0);
            acc[m] = __builtin_amdgcn_mfma_f32_16x16x32_bf16(al, B[ks], acc[m], 0, 0, 0);
        }
    }
    const int col = w * 16 + c;
    const float bv = (col < 63) ? emb_b[col] : 0.f;
    #pragma unroll
    for (int m = 0; m < 4; ++m)
        #pragma unroll
        for (int r = 0; r < 4; ++r) {
            const int node = n0 + m * 16 + q * 4 + r;
            if (node < NN) {
                const float val = (col < 63) ? acc[m][r] + bv : elem_w[node];
                x[(size_t)node * 64 + col] = val;
                xbf[(size_t)node * 64 + col] = f2bf(val);
            }
        }
}

// ================= CSR build =================
__global__ void k_deg(const int* __restrict__ self_idx, int* __restrict__ deg) {
    int e = blockIdx.x * 256 + threadIdx.x;
    if (e < NE) atomicAdd(&deg[self_idx[e]], 1);
}

__global__ void k_nodepack(const int* __restrict__ deg, int* __restrict__ nstart,
                           int* __restrict__ ctotal)
{
    __shared__ int sdeg[1024];
    __shared__ int sst[1024];
    const int c0 = blockIdx.x << 10;
    const int cnt = min(1024, NN - c0);
    for (int i = threadIdx.x; i < cnt; i += 64) sdeg[i] = deg[c0 + i];
    __syncthreads();
    if (threadIdx.x == 0) {
        int cur = 0;
        for (int i = 0; i < cnt; ++i) {
            int d = sdeg[i];
            if (d > 0 && ((cur & 63) + d > 64)) cur = (cur + 63) & ~63;
            sst[i] = cur;
            cur += d;
        }
        ctotal[blockIdx.x] = (cur + 63) & ~63;
    }
    __syncthreads();
    for (int i = threadIdx.x; i < cnt; i += 64) nstart[c0 + i] = sst[i];
}

__global__ void k_chunkscan(const int* __restrict__ ctotal, int* __restrict__ cbase) {
    __shared__ int s[256];
    int t = threadIdx.x;
    int v = (t < NCH) ? ctotal[t] : 0;
    s[t] = v;
    __syncthreads();
    for (int off = 1; off < 256; off <<= 1) {
        int add = (t >= off) ? s[t - off] : 0;
        __syncthreads();
        s[t] += add;
        __syncthreads();
    }
    if (t < NCH) cbase[t] = s[t] - v;
}

// fill gather table: gnode[slot] = (self, nbr), gwn[slot] = elem_w[nbr]
__global__ void k_fill(const int* __restrict__ self_idx, const int* __restrict__ nbr_idx,
                       const float* __restrict__ elem_w,
                       const int* __restrict__ nstart, const int* __restrict__ cbase,
                       int* __restrict__ cursor, int2* __restrict__ gnode,
                       float* __restrict__ gwn)
{
    int e = blockIdx.x * 256 + threadIdx.x;
    if (e >= NE) return;
    int n = self_idx[e];
    int r = atomicAdd(&cursor[n], 1);
    int slot = cbase[n >> 10] + nstart[n] + r;
    int nb = nbr_idx[e];
    gnode[slot] = make_int2(n, nb);
    gwn[slot] = elem_w[nb];
}

// ================= CSR gate: gate MLP, reduction via MFMA vs bcast-w2 ==============
__global__ __launch_bounds__(256, 4) void k_lgate(
    const u16* __restrict__ xbf, const int2* __restrict__ gnode,
    const float* __restrict__ gwn,
    const u16* __restrict__ gw1p, const float* __restrict__ gb1,
    const u16* __restrict__ gw2p, const float* __restrict__ gpw,
    float* __restrict__ sgf_out)
{
    __shared__ __align__(16) u16 sA[64 * 128];
    __shared__ __align__(16) u16 sH[64 * 128];
    __shared__ float sg[4][64];
    __shared__ float gfin[64], tval[64];
    __shared__ float swn[64];
    __shared__ int   snid[64];
    __shared__ short srs[64], sre[64];
    const int tid = threadIdx.x;
    const int base = blockIdx.x * 64;
    if (gnode[base].x < 0) return;

    if (tid < 64) {
        int2 nn = gnode[base + tid];
        snid[tid] = nn.x;
        swn[tid] = gwn[base + tid];
    }
    for (int i = tid; i < 64 * 16; i += 256) {
        const int row = i >> 4, g = i & 15;
        const int2 nn = gnode[base + row];
        const int node = (g < 8) ? nn.x : nn.y;
        uint4 v; v.x = 0; v.y = 0; v.z = 0; v.w = 0;
        if (node >= 0) v = *(const uint4*)(xbf + (size_t)node * 64 + (g & 7) * 8);
        *(uint4*)((char*)sA + row * 256 + ((g ^ (row & 7)) * 16)) = v;
    }
    __syncthreads();
    if (tid < 64) {
        int n = snid[tid];
        int rs = tid, re = tid + 1;
        if (n >= 0) {
            while (rs > 0 && snid[rs - 1] == n) --rs;
            while (re < 64 && snid[re] == n) ++re;
        }
        srs[tid] = (short)rs; sre[tid] = (short)re;
    }

    const int w = tid >> 6, lane = tid & 63, q = lane >> 4, c = lane & 15;

    #pragma unroll 1
    for (int h = 0; h < 3; ++h) {
        f32x4 acc2[4];
        #pragma unroll
        for (int m = 0; m < 4; ++m) acc2[m] = 0.f;
        const u16* wp = gw1p + (size_t)h * 128 * 256;
        #pragma unroll 1
        for (int half = 0; half < 2; ++half) {
            f32x4 acc[4][2];
            #pragma unroll
            for (int m = 0; m < 4; ++m) { acc[m][0] = 0.f; acc[m][1] = 0.f; }
            __builtin_amdgcn_s_setprio(1);
            #pragma unroll 2
            for (int ks = 0; ks < 4; ++ks) {
                s16x8 B1[2];
                #pragma unroll
                for (int n2 = 0; n2 < 2; ++n2)
                    B1[n2] = *(const s16x8*)(wp + ((size_t)(ks * 16 + w * 4 + half * 2 + n2) * 64 + lane) * 8);
                s16x8 a[4];
                #pragma unroll
                for (int m = 0; m < 4; ++m) {
                    const int row = m * 16 + c;
                    a[m] = *(const s16x8*)((const char*)sA + row * 256 + (((ks * 4 + q) ^ (row & 7)) * 16));
                }
                #pragma unroll
                for (int n2 = 0; n2 < 2; ++n2)
                    #pragma unroll
                    for (int m = 0; m < 4; ++m)
                        acc[m][n2] = __builtin_amdgcn_mfma_f32_16x16x32_bf16(a[m], B1[n2], acc[m][n2], 0, 0, 0);
            }
            __builtin_amdgcn_s_setprio(0);

            __syncthreads();   // prev sH consumers done
            const float b1a = gb1[h * 256 + w * 64 + (half * 2 + 0) * 16 + c];
            const float b1b = gb1[h * 256 + w * 64 + (half * 2 + 1) * 16 + c];
            #pragma unroll
            for (int m = 0; m < 4; ++m)
                #pragma unroll
                for (int r = 0; r < 4; ++r) {
                    const int row = m * 16 + q * 4 + r;
                    const u32 pk = cvtpk(lrelu(acc[m][0][r] + b1a), lrelu(acc[m][1][r] + b1b));
                    *(u32*)((char*)sH + row * 256 + (((w * 4 + (c >> 2)) ^ (row & 7)) * 16) + (c & 3) * 4) = pk;
                }
            // gate w2 frag (col-broadcast); wave w takes K-quarter kk=w of this half
            s16x8 B2 = *(const s16x8*)(gw2p + ((size_t)(h * 8 + half * 4 + w) * 64 + lane) * 8);
            __syncthreads();

            __builtin_amdgcn_s_setprio(1);
            #pragma unroll
            for (int m = 0; m < 4; ++m) {
                const int row = m * 16 + c;
                s16x8 a2 = *(const s16x8*)((const char*)sH + row * 256 + (((w * 4 + q) ^ (row & 7)) * 16));
                acc2[m] = __builtin_amdgcn_mfma_f32_16x16x32_bf16(a2, B2, acc2[m], 0, 0, 0);
            }
            __builtin_amdgcn_s_setprio(0);
        }
        // all cols identical (bcast w2): lane c==0 publishes its 16 rows
        if (c == 0) {
            #pragma unroll
            for (int m = 0; m < 4; ++m)
                #pragma unroll
                for (int r = 0; r < 4; ++r)
                    sg[w][m * 16 + q * 4 + r] = acc2[m][r];
        }
        __syncthreads();
        if (tid < 64)
            gfin[tid] = (snid[tid] >= 0) ? sg[0][tid] + sg[1][tid] + sg[2][tid] + sg[3][tid] : -1e30f;
        __syncthreads();
        if (tid < 64) {
            const int rs = srs[tid], re = sre[tid];
            float m = -1e30f;
            for (int j = rs; j < re; ++j) m = fmaxf(m, gfin[j]);
            tval[tid] = (snid[tid] >= 0) ? powf(swn[tid], gpw[h]) * expf(gfin[tid] - m) : 0.f;
        }
        __syncthreads();
        if (tid < 64) {
            const int rs = srs[tid], re = sre[tid];
            float d = 1e-10f;
            for (int j = rs; j < re; ++j) d += tval[j];
            sgf_out[SSTR * h + base + tid] = tval[tid] / d;
        }
        __syncthreads();
    }
}

// ================= CSR msg: msg MLP + block-local pooling =================
__global__ __launch_bounds__(256, 4) void k_lmsg(
    const u16* __restrict__ xbf, const int2* __restrict__ gnode,
    const u16* __restrict__ mw1p, const float* __restrict__ mb1,
    const u16* __restrict__ mw2p, const float* __restrict__ mb2,
    const float* __restrict__ sgf_in, float* __restrict__ pooled)
{
    __shared__ __align__(16) u16 sA[64 * 128];
    __shared__ __align__(16) u16 sH[64 * 128];
    __shared__ float sgfl[64][3];
    __shared__ int   snid[64];
    __shared__ short srs[64], sre[64];
    const int tid = threadIdx.x;
    const int base = blockIdx.x * 64;
    if (gnode[base].x < 0) return;

    if (tid < 64) snid[tid] = gnode[base + tid].x;
    if (tid < 192) {
        const int row = tid / 3, h = tid % 3;
        sgfl[row][h] = sgf_in[SSTR * h + base + row];
    }
    for (int i = tid; i < 64 * 16; i += 256) {
        const int row = i >> 4, g = i & 15;
        const int2 nn = gnode[base + row];
        const int node = (g < 8) ? nn.x : nn.y;
        uint4 v; v.x = 0; v.y = 0; v.z = 0; v.w = 0;
        if (node >= 0) v = *(const uint4*)(xbf + (size_t)node * 64 + (g & 7) * 8);
        *(uint4*)((char*)sA + row * 256 + ((g ^ (row & 7)) * 16)) = v;
    }
    __syncthreads();
    if (tid < 64) {
        int n = snid[tid];
        int rs = tid, re = tid + 1;
        if (n >= 0) {
            while (rs > 0 && snid[rs - 1] == n) --rs;
            while (re < 64 && snid[re] == n) ++re;
        }
        srs[tid] = (short)rs; sre[tid] = (short)re;
    }

    const int w = tid >> 6, lane = tid & 63, q = lane >> 4, c = lane & 15;
    float wacc[4][4];
    #pragma unroll
    for (int m = 0; m < 4; ++m)
        #pragma unroll
        for (int r = 0; r < 4; ++r) wacc[m][r] = 0.f;

    #pragma unroll 1
    for (int h = 0; h < 3; ++h) {
        const u16* wp = mw1p + (size_t)h * 128 * 256;
        #pragma unroll 1
        for (int half = 0; half < 2; ++half) {
            f32x4 acc[4][2];
            #pragma unroll
            for (int m = 0; m < 4; ++m) { acc[m][0] = 0.f; acc[m][1] = 0.f; }
            __builtin_amdgcn_s_setprio(1);
            #pragma unroll 2
            for (int ks = 0; ks < 4; ++ks) {
                s16x8 B1[2];
                #pragma unroll
                for (int n2 = 0; n2 < 2; ++n2)
                    B1[n2] = *(const s16x8*)(wp + ((size_t)(ks * 16 + w * 4 + half * 2 + n2) * 64 + lane) * 8);
                s16x8 a[4];
                #pragma unroll
                for (int m = 0; m < 4; ++m) {
                    const int row = m * 16 + c;
                    a[m] = *(const s16x8*)((const char*)sA + row * 256 + (((ks * 4 + q) ^ (row & 7)) * 16));
                }
                #pragma unroll
                for (int n2 = 0; n2 < 2; ++n2)
                    #pragma unroll
                    for (int m = 0; m < 4; ++m)
                        acc[m][n2] = __builtin_amdgcn_mfma_f32_16x16x32_bf16(a[m], B1[n2], acc[m][n2], 0, 0, 0);
            }
            __builtin_amdgcn_s_setprio(0);

            __syncthreads();
            const float b1a = mb1[h * 256 + w * 64 + (half * 2 + 0) * 16 + c];
            const float b1b = mb1[h * 256 + w * 64 + (half * 2 + 1) * 16 + c];
            #pragma unroll
            for (int m = 0; m < 4; ++m)
                #pragma unroll
                for (int r = 0; r < 4; ++r) {
                    const int row = m * 16 + q * 4 + r;
                    const u32 pk = cvtpk(lrelu(acc[m][0][r] + b1a), lrelu(acc[m][1][r] + b1b));
                    *(u32*)((char*)sH + row * 256 + (((w * 4 + (c >> 2)) ^ (row & 7)) * 16) + (c & 3) * 4) = pk;
                }
            s16x8 B2[4];
            #pragma unroll
            for (int k2 = 0; k2 < 4; ++k2)
                B2[k2] = *(const s16x8*)(mw2p + (size_t)h * 256 * 64 + ((size_t)((half * 4 + k2) * 4 + w) * 64 + lane) * 8);
            __syncthreads();

            f32x4 acc2[4];
            #pragma unroll
            for (int m = 0; m < 4; ++m) acc2[m] = 0.f;
            __builtin_amdgcn_s_setprio(1);
            #pragma unroll
            for (int k2 = 0; k2 < 4; ++k2) {
                #pragma unroll
                for (int m2 = 0; m2 < 4; ++m2) {
                    const int row = m2 * 16 + c;
                    s16x8 a2 = *(const s16x8*)((const char*)sH + row * 256 + (((k2 * 4 + q) ^ (row & 7)) * 16));
                    acc2[m2] = __builtin_amdgcn_mfma_f32_16x16x32_bf16(a2, B2[k2], acc2[m2], 0, 0, 0);
                }
            }
            __builtin_amdgcn_s_setprio(0);
            const float b2v = half ? mb2[h * 64 + w * 16 + c] : 0.f;
            #pragma unroll
            for (int m2 = 0; m2 < 4; ++m2)
                #pragma unroll
                for (int r = 0; r < 4; ++r) {
                    const int row = m2 * 16 + q * 4 + r;
                    wacc[m2][r] += (acc2[m2][r] + b2v) * sgfl[row][h];
                }
        }
        __syncthreads();
    }

    float* waccL = (float*)sH;
    #pragma unroll
    for (int m = 0; m < 4; ++m)
        #pragma unroll
        for (int r = 0; r < 4; ++r)
            waccL[(m * 16 + q * 4 + r) * 64 + w * 16 + c] = wacc[m][r];
    __syncthreads();
    {
        const int col = tid & 63, grp = tid >> 6;
        for (int i = grp; i < 64; i += 4) {
            const int n = snid[i];
            if (n >= 0 && srs[i] == (short)i) {
                float s = 0.f;
                const int re = sre[i];
                for (int j = i; j < re; ++j) s += waccL[j * 64 + col];
                pooled[(size_t)n * 64 + col] = s * (1.f / 3.f);
            }
        }
    }
}

// ---------- residual + refresh bf16 mirror ----------
__global__ void k_mirror2(float* __restrict__ x, const float* __restrict__ pooled,
                          u16* __restrict__ xbf, int n4)
{
    int i = blockIdx.x * 256 + threadIdx.x;
    if (i >= n4) return;
    float4 xv = *(const float4*)(x + (size_t)i * 4);
    float4 pv = *(const float4*)(pooled + (size_t)i * 4);
    xv.x += pv.x; xv.y += pv.y; xv.z += pv.z; xv.w += pv.w;
    *(float4*)(x + (size_t)i * 4) = xv;
    uint2 o;
    o.x = cvtpk(xv.x, xv.y);
    o.y = cvtpk(xv.z, xv.w);
    *(uint2*)(xbf + (size_t)i * 4) = o;
}

// ================= crystal path (R11, streamed B1, (256,4)) =================
template<int KD, bool GATHER>
__global__ __launch_bounds__(256, 4) void k_gate(
    const u16* __restrict__ xbf, const int* __restrict__ sidx, const int* __restrict__ nidx,
    const int* __restrict__ scat, const u16* __restrict__ w1p,
    const float* __restrict__ b1g, const float* __restrict__ w2g,
    float* __restrict__ gate_out, u32* __restrict__ gmax, int nrows, size_t gstride)
{
    constexpr int KS = KD / 32;
    constexpr int RB = KD * 2;
    constexpr int G  = KD / 8;
    __shared__ __align__(16) u16 sA[64 * KD];
    __shared__ float sg[4][64];
    const int tid = threadIdx.x;
    const int r0 = blockIdx.x * 64;
    const int rem = min(64, nrows - r0);

    for (int i = tid; i < 64 * G; i += 256) {
        const int row = i / G, g = i % G;
        const int rr = (row < rem) ? row : 0;
        uint4 v;
        if (GATHER) {
            const int node = (g < G / 2) ? sidx[r0 + rr] : nidx[r0 + rr];
            v = *(const uint4*)(xbf + (size_t)node * 64 + (g & (G / 2 - 1)) * 8);
        } else {
            v = *(const uint4*)(xbf + (size_t)(r0 + rr) * 64 + g * 8);
        }
        *(uint4*)((char*)sA + row * RB + ((g ^ (row & 7)) * 16)) = v;
    }
    __syncthreads();

    const int w = tid >> 6, lane = tid & 63, q = lane >> 4, c = lane & 15;

    #pragma unroll 1
    for (int h = 0; h < 3; ++h) {
        float part[4][4];
        #pragma unroll
        for (int m = 0; m < 4; ++m)
            #pragma unroll
            for (int r = 0; r < 4; ++r) part[m][r] = 0.f;
        const u16* wp = w1p + (size_t)h * KD * 256;
        #pragma unroll 1
        for (int half = 0; half < 2; ++half) {
            f32x4 acc[4][2];
            #pragma unroll
            for (int m = 0; m < 4; ++m) { acc[m][0] = 0.f; acc[m][1] = 0.f; }
            __builtin_amdgcn_s_setprio(1);
            #pragma unroll 2
            for (int ks = 0; ks < KS; ++ks) {
                s16x8 B1[2];
                #pragma unroll
                for (int n2 = 0; n2 < 2; ++n2)
                    B1[n2] = *(const s16x8*)(wp + ((size_t)(ks * 16 + w * 4 + half * 2 + n2) * 64 + lane) * 8);
                s16x8 a[4];
                #pragma unroll
                for (int m = 0; m < 4; ++m) {
                    const int row = m * 16 + c;
                    a[m] = *(const s16x8*)((const char*)sA + row * RB + (((ks * 4 + q) ^ (row & 7)) * 16));
                }
                #pragma unroll
                for (int n2 = 0; n2 < 2; ++n2)
                    #pragma unroll
                    for (int m = 0; m < 4; ++m)
                        acc[m][n2] = __builtin_amdgcn_mfma_f32_16x16x32_bf16(a[m], B1[n2], acc[m][n2], 0, 0, 0);
            }
            __builtin_amdgcn_s_setprio(0);
            #pragma unroll
            for (int n2 = 0; n2 < 2; ++n2) {
                const int col = w * 64 + (half * 2 + n2) * 16 + c;
                const float b1v = b1g[h * 256 + col];
                const float w2v = w2g[h * 256 + col];
                #pragma unroll
                for (int m = 0; m < 4; ++m)
                    #pragma unroll
                    for (int r = 0; r < 4; ++r)
                        part[m][r] += lrelu(acc[m][n2][r] + b1v) * w2v;
            }
        }
        #pragma unroll
        for (int off = 1; off < 16; off <<= 1)
            #pragma unroll
            for (int m = 0; m < 4; ++m)
                #pragma unroll
                for (int r = 0; r < 4; ++r)
                    part[m][r] += __shfl_xor(part[m][r], off, 64);
        if (c == 0) {
            #pragma unroll
            for (int m = 0; m < 4; ++m)
                #pragma unroll
                for (int r = 0; r < 4; ++r)
                    sg[w][m * 16 + q * 4 + r] = part[m][r];
        }
        __syncthreads();
        if (tid < rem) {
            const float gv = sg[0][tid] + sg[1][tid] + sg[2][tid] + sg[3][tid];
            gate_out[gstride * h + r0 + tid] = gv;
            atomicMax(&gmax[scat[r0 + tid] * 3 + h], encf(gv));
        }
        __syncthreads();
    }
}

template<int KD, bool GATHER>
__global__ __launch_bounds__(256, 4) void k_msg(
    const u16* __restrict__ xbf, const int* __restrict__ sidx, const int* __restrict__ nidx,
    const int* __restrict__ scat, const u16* __restrict__ w1p, const float* __restrict__ b1g,
    const u16* __restrict__ w2p, const float* __restrict__ b2g,
    const float* __restrict__ tbuf, const float* __restrict__ den,
    float* __restrict__ outp, int nrows, size_t gstride)
{
    constexpr int KS = KD / 32;
    constexpr int RB = KD * 2;
    constexpr int G  = KD / 8;
    __shared__ __align__(16) u16 sA[64 * KD];
    __shared__ __align__(16) u16 sH[64 * 128];
    __shared__ float sgf[64][3];
    __shared__ int ssi[64];
    const int tid = threadIdx.x;
    const int r0 = blockIdx.x * 64;
    const int rem = min(64, nrows - r0);

    for (int i = tid; i < 64 * G; i += 256) {
        const int row = i / G, g = i % G;
        const int rr = (row < rem) ? row : 0;
        uint4 v;
        if (GATHER) {
            const int node = (g < G / 2) ? sidx[r0 + rr] : nidx[r0 + rr];
            v = *(const uint4*)(xbf + (size_t)node * 64 + (g & (G / 2 - 1)) * 8);
        } else {
            v = *(const uint4*)(xbf + (size_t)(r0 + rr) * 64 + g * 8);
        }
        *(uint4*)((char*)sA + row * RB + ((g ^ (row & 7)) * 16)) = v;
    }
    if (tid < 64) ssi[tid] = (tid < rem) ? scat[r0 + tid] : 0;
    if (tid < 192) {
        const int row = tid / 3, h = tid % 3;
        if (row < rem) {
            const int s = scat[r0 + row] * 3 + h;
            sgf[row][h] = tbuf[gstride * h + r0 + row] / (den[s] + 1e-10f);
        } else {
            sgf[row][h] = 0.f;
        }
    }
    __syncthreads();

    const int w = tid >> 6, lane = tid & 63, q = lane >> 4, c = lane & 15;
    float wacc[4][4];
    #pragma unroll
    for (int m = 0; m < 4; ++m)
        #pragma unroll
        for (int r = 0; r < 4; ++r) wacc[m][r] = 0.f;

    #pragma unroll 1
    for (int h = 0; h < 3; ++h) {
        const u16* wp = w1p + (size_t)h * KD * 256;
        #pragma unroll 1
        for (int half = 0; half < 2; ++half) {
            f32x4 acc[4][2];
            #pragma unroll
            for (int m = 0; m < 4; ++m) { acc[m][0] = 0.f; acc[m][1] = 0.f; }
            __builtin_amdgcn_s_setprio(1);
            #pragma unroll 2
            for (int ks = 0; ks < KS; ++ks) {
                s16x8 B1[2];
                #pragma unroll
                for (int n2 = 0; n2 < 2; ++n2)
                    B1[n2] = *(const s16x8*)(wp + ((size_t)(ks * 16 + w * 4 + half * 2 + n2) * 64 + lane) * 8);
                s16x8 a[4];
                #pragma unroll
                for (int m = 0; m < 4; ++m) {
                    const int row = m * 16 + c;
                    a[m] = *(const s16x8*)((const char*)sA + row * RB + (((ks * 4 + q) ^ (row & 7)) * 16));
                }
                #pragma unroll
                for (int n2 = 0; n2 < 2; ++n2)
                    #pragma unroll
                    for (int m = 0; m < 4; ++m)
                        acc[m][n2] = __builtin_amdgcn_mfma_f32_16x16x32_bf16(a[m], B1[n2], acc[m][n2], 0, 0, 0);
            }
            __builtin_amdgcn_s_setprio(0);

            __syncthreads();
            const float b1a = b1g[h * 256 + w * 64 + (half * 2 + 0) * 16 + c];
            const float b1b = b1g[h * 256 + w * 64 + (half * 2 + 1) * 16 + c];
            #pragma unroll
            for (int m = 0; m < 4; ++m)
                #pragma unroll
                for (int r = 0; r < 4; ++r) {
                    const int row = m * 16 + q * 4 + r;
                    const u32 pk = cvtpk(lrelu(acc[m][0][r] + b1a), lrelu(acc[m][1][r] + b1b));
                    *(u32*)((char*)sH + row * 256 + (((w * 4 + (c >> 2)) ^ (row & 7)) * 16) + (c & 3) * 4) = pk;
                }
            s16x8 B2[4];
            #pragma unroll
            for (int k2 = 0; k2 < 4; ++k2)
                B2[k2] = *(const s16x8*)(w2p + (size_t)h * 256 * 64 + ((size_t)((half * 4 + k2) * 4 + w) * 64 + lane) * 8);
            __syncthreads();

            f32x4 acc2[4];
            #pragma unroll
            for (int m = 0; m < 4; ++m) acc2[m] = 0.f;
            __builtin_amdgcn_s_setprio(1);
            #pragma unroll
            for (int k2 = 0; k2 < 4; ++k2) {
                #pragma unroll
                for (int m2 = 0; m2 < 4; ++m2) {
                    const int row = m2 * 16 + c;
                    s16x8 a2 = *(const s16x8*)((const char*)sH + row * 256 + (((k2 * 4 + q) ^ (row & 7)) * 16));
                    acc2[m2] = __builtin_amdgcn_mfma_f32_16x16x32_bf16(a2, B2[k2], acc2[m2], 0, 0, 0);
                }
            }
            __builtin_amdgcn_s_setprio(0);
            const float b2v = half ? b2g[h * 64 + w * 16 + c] : 0.f;
            #pragma unroll
            for (int m2 = 0; m2 < 4; ++m2)
                #pragma unroll
                for (int r = 0; r < 4; ++r) {
                    const int row = m2 * 16 + q * 4 + r;
                    wacc[m2][r] += (acc2[m2][r] + b2v) * sgf[row][h];
                }
        }
    }
    #pragma unroll
    for (int m = 0; m < 4; ++m)
        #pragma unroll
        for (int r = 0; r < 4; ++r) {
            const int row = m * 16 + q * 4 + r;
            if (row < rem)
                atomicAdd(&outp[(size_t)ssi[row] * 64 + w * 16 + c], wacc[m][r] * (1.f / 3.f));
        }
}

__global__ void k_seg_exp(float* __restrict__ gate_t, const int* __restrict__ idx,
                          const int* __restrict__ wi, const float* __restrict__ elem_w,
                          const float* __restrict__ pw, const u32* __restrict__ gmax,
                          float* __restrict__ den, int n, size_t gstride)
{
    int e = blockIdx.x * blockDim.x + threadIdx.x;
    if (e >= n) return;
    int s = idx[e] * 3;
    float wgt = elem_w[wi ? wi[e] : e];
    #pragma unroll
    for (int h = 0; h < 3; ++h) {
        float gm = decf(gmax[s + h]);
        float t = powf(wgt, pw[h]) * expf(gate_t[gstride * h + e] - gm);
        gate_t[gstride * h + e] = t;
        atomicAdd(&den[s + h], t);
    }
}

extern "C" void kernel_launch(void* const* d_in, const int* in_sizes, int n_in,
                              void* d_out, int out_size, void* d_ws, size_t ws_size,
                              hipStream_t stream)
{
    const float* elem_w   = (const float*)d_in[0];
    const float* elem_fea = (const float*)d_in[1];
    const int*   self_idx = (const int*)d_in[2];
    const int*   nbr_idx  = (const int*)d_in[3];
    const int*   cry_idx  = (const int*)d_in[4];
    const float* emb_w    = (const float*)d_in[5];
    const float* emb_b    = (const float*)d_in[6];
    const float* gg_w1    = (const float*)d_in[7];
    const float* gg_b1    = (const float*)d_in[8];
    const float* gg_w2    = (const float*)d_in[9];
    const float* gm_w1    = (const float*)d_in[11];
    const float* gm_b1    = (const float*)d_in[12];
    const float* gm_w2    = (const float*)d_in[13];
    const float* gm_b2    = (const float*)d_in[14];
    const float* g_pow    = (const float*)d_in[15];
    const float* cg_w1    = (const float*)d_in[16];
    const float* cg_b1    = (const float*)d_in[17];
    const float* cg_w2    = (const float*)d_in[18];
    const float* cm_w1    = (const float*)d_in[20];
    const float* cm_b1    = (const float*)d_in[21];
    const float* cm_w2    = (const float*)d_in[22];
    const float* cm_b2    = (const float*)d_in[23];
    const float* c_pow    = (const float*)d_in[24];

    char* wsp = (char*)d_ws;
    size_t off = 0;
    auto alloc = [&](size_t b) { char* p = wsp + off; off += (b + 255) & ~(size_t)255; return p; };
    float* x      = (float*)alloc((size_t)NN * 64 * 4);
    float* pooled = (float*)alloc((size_t)NN * 64 * 4);
    u16*   xbf    = (u16*)  alloc((size_t)NN * 64 * 2);
    float* sgf    = (float*)alloc((size_t)3 * SSTR * 4);
    float* gate_t = (float*)alloc((size_t)NN * 3 * 4);   // crystal planar [3][NN]
    float* cden   = (float*)alloc((size_t)NC * 3 * 4);
    u32*   cgmax  = (u32*)  alloc((size_t)NC * 3 * 4);
    int* deg    = (int*)alloc((size_t)NN * 4);
    int* nstart = (int*)alloc((size_t)NN * 4);
    int* cursor = (int*)alloc((size_t)NN * 4);
    int* ctotal = (int*)alloc((size_t)NCH * 4);
    int* cbase  = (int*)alloc((size_t)NCH * 4);
    int2* gnode = (int2*)alloc((size_t)NBLK * 64 * 8);
    float* gwn  = (float*)alloc((size_t)NBLK * 64 * 4);
    u16* wg1p = (u16*)alloc((size_t)9 * 128 * 256 * 2);
    u16* wm1p = (u16*)alloc((size_t)9 * 128 * 256 * 2);
    u16* wm2p = (u16*)alloc((size_t)9 * 256 * 64 * 2);
    u16* wg2p = (u16*)alloc((size_t)9 * 8 * 64 * 8 * 2);
    u16* cg1p = (u16*)alloc((size_t)3 * 64 * 256 * 2);
    u16* cm1p = (u16*)alloc((size_t)3 * 64 * 256 * 2);
    u16* cm2p = (u16*)alloc((size_t)3 * 256 * 64 * 2);
    u16* webp = (u16*)alloc((size_t)224 * 64 * 2);

    auto pack = [&](const float* s, u16* d, int K, int N, int H) {
        int tot = H * (K / 32) * (N / 16) * 64;
        k_pack<<<(tot + 255) / 256, 256, 0, stream>>>(s, d, K, N, H);
    };
    pack(gg_w1, wg1p, 128, 256, 9);
    pack(gm_w1, wm1p, 128, 256, 9);
    pack(cg_w1, cg1p, 64, 256, 3);
    pack(cm_w1, cm1p, 64, 256, 3);
    k_pack2<<<(9 * 32 * 64 + 255) / 256, 256, 0, stream>>>(gm_w2, wm2p, 9);
    k_pack2<<<(3 * 32 * 64 + 255) / 256, 256, 0, stream>>>(cm_w2, cm2p, 3);
    k_packg<<<(9 * 8 * 64 + 255) / 256, 256, 0, stream>>>(gg_w2, wg2p, 9);
    k_packe<<<7, 256, 0, stream>>>(emb_w, webp);

    // CSR build
    hipMemsetAsync(deg, 0, (size_t)NN * 4, stream);
    hipMemsetAsync(cursor, 0, (size_t)NN * 4, stream);
    hipMemsetAsync(gnode, 0xFF, (size_t)NBLK * 64 * 8, stream);
    k_deg<<<(NE + 255) / 256, 256, 0, stream>>>(self_idx, deg);
    k_nodepack<<<NCH, 64, 0, stream>>>(deg, nstart, ctotal);
    k_chunkscan<<<1, 256, 0, stream>>>(ctotal, cbase);
    k_fill<<<(NE + 255) / 256, 256, 0, stream>>>(self_idx, nbr_idx, elem_w,
                                                 nstart, cbase, cursor, gnode, gwn);

    k_embed_mm<<<(NN + 63) / 64, 256, 0, stream>>>(elem_fea, elem_w, webp, emb_b, x, xbf);

    for (int l = 0; l < 3; ++l) {
        hipMemsetAsync(pooled, 0, (size_t)NN * 64 * 4, stream);
        k_lgate<<<NBLK, 256, 0, stream>>>(
            xbf, gnode, gwn,
            wg1p + (size_t)l * 3 * 128 * 256, gg_b1 + l * 768,
            wg2p + (size_t)l * 3 * 8 * 64 * 8, g_pow + l * 3, sgf);
        k_lmsg<<<NBLK, 256, 0, stream>>>(
            xbf, gnode,
            wm1p + (size_t)l * 3 * 128 * 256, gm_b1 + l * 768,
            wm2p + (size_t)l * 3 * 256 * 64, gm_b2 + l * 192, sgf, pooled);
        k_mirror2<<<(NN * 64 / 4 + 255) / 256, 256, 0, stream>>>(x, pooled, xbf, NN * 64 / 4);
    }

    hipMemsetAsync(cgmax, 0, (size_t)NC * 3 * 4, stream);
    hipMemsetAsync(cden, 0, (size_t)NC * 3 * 4, stream);
    hipMemsetAsync(d_out, 0, (size_t)NC * 64 * 4, stream);
    const int GN = (NN + 63) / 64;
    k_gate<64, false><<<GN, 256, 0, stream>>>(
        xbf, nullptr, nullptr, cry_idx, cg1p, cg_b1, cg_w2, gate_t, cgmax, NN, (size_t)NN);
    k_seg_exp<<<(NN + 255) / 256, 256, 0, stream>>>(
        gate_t, cry_idx, nullptr, elem_w, c_pow, cgmax, cden, NN, (size_t)NN);
    k_msg<64, false><<<GN, 256, 0, stream>>>(
        xbf, nullptr, nullptr, cry_idx, cm1p, cm_b1, cm2p, cm_b2,
        gate_t, cden, (float*)d_out, NN, (size_t)NN);
}